// Round 18
// baseline (706.924 us; speedup 1.0000x reference)
//
#include <hip/hip_runtime.h>
#include <hip/hip_bf16.h>
#include <cmath>

#define T_  128
#define B_  128
#define I_  256
#define H_  256
#define G4_ 1024

#define NP1 512    // phase1 blocks: (t, col-quarter)
#define NRP 8192   // repack blocks: 64 per t

using frag  = __attribute__((ext_vector_type(8))) short;   // 8 bf16 = 4 VGPR
using f32x4 = __attribute__((ext_vector_type(4))) float;
using u32x4 = __attribute__((ext_vector_type(4))) unsigned int;

__device__ __forceinline__ unsigned short bf16u(float f) {
    __hip_bfloat16 b = __float2bfloat16(f);
    return __builtin_bit_cast(unsigned short, b);
}

#define BARRIER_SEQ() do {                                   \
    __builtin_amdgcn_sched_barrier(0);                       \
    asm volatile("s_waitcnt lgkmcnt(0)" ::: "memory");       \
    __builtin_amdgcn_s_barrier();                            \
    __builtin_amdgcn_sched_barrier(0);                       \
} while (0)

// ================= Fused pre-pass (round-16, verbatim) =========================
__global__ __launch_bounds__(512)
void lstm_pre(const float* __restrict__ x, const float* __restrict__ Wi,
              const float* __restrict__ bi, const float* __restrict__ bh,
              const float* __restrict__ Wh,
              float* __restrict__ Gxp, unsigned short* __restrict__ Whp)
{
    const int bid = blockIdx.x;
    const int tid = threadIdx.x;

    if (bid >= NP1) {
        // ---------------- repack role ----------------
        const int pbid = bid - NP1;
        const int tt   = pbid >> 6;
        const int j64  = pbid & 63;
        const int gid  = tt * 32768 + j64 * 512 + tid;
        const int lane = gid & 63;
        const int kb   = (gid >> 12) & 7;
        const int nb   = (gid >> 6) & 63;
        const int k0   = kb * 32 + (lane >> 4) * 8;
        const int col  = nb * 16 + (lane & 15);
        const float* src = Wh + (size_t)(tt * I_ + k0) * G4_ + col;
        unsigned short v[8];
        #pragma unroll
        for (int j = 0; j < 8; ++j) v[j] = bf16u(src[(size_t)j * G4_]);
        uint4 o;
        o.x = v[0] | ((unsigned)v[1] << 16);
        o.y = v[2] | ((unsigned)v[3] << 16);
        o.z = v[4] | ((unsigned)v[5] << 16);
        o.w = v[6] | ((unsigned)v[7] << 16);
        *(uint4*)(Whp + (size_t)gid * 8) = o;
        return;
    }

    // ---------------- phase1-MFMA role ----------------
    __shared__ unsigned short ws[2][16][64][8];   // 32KB

    const int t    = bid >> 2;
    const int q    = bid & 3;
    const int wv   = tid >> 6;
    const int lane = tid & 63;
    const int lrow = lane & 15;
    const int lhi  = lane >> 4;

    frag af[8];
    #pragma unroll
    for (int kb = 0; kb < 8; ++kb) {
        const float* ap = x + ((size_t)(t * B_ + wv * 16 + lrow) * I_ + kb * 32 + lhi * 8);
        float4 f0 = *(const float4*)ap;
        float4 f1 = *(const float4*)(ap + 4);
        u32x4 p;
        p.x = bf16u(f0.x) | ((unsigned)bf16u(f0.y) << 16);
        p.y = bf16u(f0.z) | ((unsigned)bf16u(f0.w) << 16);
        p.z = bf16u(f1.x) | ((unsigned)bf16u(f1.y) << 16);
        p.w = bf16u(f1.z) | ((unsigned)bf16u(f1.w) << 16);
        af[kb] = __builtin_bit_cast(frag, p);
    }

    f32x4 acc[16];
    #pragma unroll
    for (int n = 0; n < 16; ++n) {
        const int gc = (q * 16 + n) * 16 + lrow;
        const float b = bi[(size_t)t * G4_ + gc] + bh[(size_t)t * G4_ + gc];
        acc[n] = (f32x4){b, b, b, b};
    }

    auto stage = [&](int kb, int b) {
        #pragma unroll
        for (int p = 0; p < 2; ++p) {
            const int task = p * 512 + tid;
            const int colL = task & 255;
            const int khi  = task >> 8;
            const float* src = Wi + ((size_t)(t * I_ + kb * 32 + khi * 8) * G4_
                                     + q * 256 + colL);
            unsigned short v[8];
            #pragma unroll
            for (int j = 0; j < 8; ++j) v[j] = bf16u(src[(size_t)j * G4_]);
            uint4 o;
            o.x = v[0] | ((unsigned)v[1] << 16);
            o.y = v[2] | ((unsigned)v[3] << 16);
            o.z = v[4] | ((unsigned)v[5] << 16);
            o.w = v[6] | ((unsigned)v[7] << 16);
            const int nbh = colL >> 4;
            const int lw  = (colL & 15) | (khi << 4);
            *(uint4*)&ws[b][nbh][lw][0] = o;
        }
    };

    stage(0, 0);
    __syncthreads();
    for (int kb = 0; kb < 8; ++kb) {
        if (kb < 7) stage(kb + 1, (kb + 1) & 1);
        #pragma unroll
        for (int n = 0; n < 16; ++n) {
            frag bf = *(const frag*)&ws[kb & 1][n][lane][0];
            acc[n] = __builtin_amdgcn_mfma_f32_16x16x32_bf16(af[kb], bf, acc[n], 0, 0, 0);
        }
        __syncthreads();
    }

    #pragma unroll
    for (int n = 0; n < 16; ++n)
        *(f32x4*)&Gxp[(((size_t)t * 8 + wv) * 64 + q * 16 + n) * 256 + lane * 4] = acc[n];
}

// ================= Phase 2: no-reduce recurrence (4 compute + 4 poller waves) ==
// 32 blocks (rg=bid&7 rows, sl=bid>>3 cols) x 512 thr, ONE barrier per step.
// Waves 0-3 (compute): wave cb does FULL K (8 kb) x 4 gates for its 16 own
//   cols -> gates complete in-wave: no LDS reduce, no barrier A. Epilogue +
//   batched publish fire right after the wave's last MFMA. 4-deep ring
//   (R4-R6 proven; NOT round-7's 8-deep sunk ring). s_setprio(1).
// Waves 4-7 (pollers): round-12's PROVEN batched agent-atomic poll loop
//   (12 words/thread, one LLC latency per round; no sc0 — rounds-8/9/11 law),
//   writing foreign h into h2[(t+1)&1] while compute waves run step t.
// Barrier B only: h2[(t+1)&1] complete (compute wrote own cols, pollers
// foreign) before step t+1's MFMA reads it. Double-buffered h2 -> no WAR.
__global__ __launch_bounds__(512, 1)
void lstm_rec(const float* __restrict__ h0, const float* __restrict__ c0in,
              const unsigned short* __restrict__ Whp,
              const float* __restrict__ Gxp, float* __restrict__ out,
              unsigned int* __restrict__ pub)
{
    __shared__ unsigned short h2[2][16][272];   // 17408 B

    const int tid  = threadIdx.x;
    const int wv   = tid >> 6;
    const int lane = tid & 63;
    const int rg   = blockIdx.x & 7;
    const int sl   = blockIdx.x >> 3;
    const int r0   = rg * 16;
    const int oc0  = sl * 64;
    const int lrow = lane & 15;
    const int lhi  = lane >> 4;

    {   // stage h0 -> h2[0] (all 512 threads)
        int row = tid >> 5;
        int cc  = (tid & 31) * 8;
        #pragma unroll
        for (int j = 0; j < 8; ++j)
            h2[0][row][cc + j] = bf16u(h0[(size_t)(r0 + row) * H_ + cc + j]);
    }
    __syncthreads();

    if (wv < 4) {
        // ======================= compute role =======================
        __builtin_amdgcn_s_setprio(1);
        const int cb   = wv;
        const int colb = oc0 + cb * 16 + lrow;

        float cst[4];
        #pragma unroll
        for (int rgi = 0; rgi < 4; ++rgi)
            cst[rgi] = c0in[(size_t)(r0 + lhi * 4 + rgi) * H_ + colb];

        const unsigned short* wl = Whp + (size_t)lane * 8;
        const float*          gl = Gxp + (size_t)lane * 4;

        // 4-deep ring over stream phase p = t*8+kb: br[kb&3][g]
        frag br[4][4];
        #pragma unroll
        for (int c = 0; c < 4; ++c)
            #pragma unroll
            for (int g = 0; g < 4; ++g)
                br[c][g] = *(const frag*)(wl +
                    (size_t)(c * 64 + g * 16 + sl * 4 + cb) * 512);

        f32x4 gxr[4];
        #pragma unroll
        for (int g = 0; g < 4; ++g)
            gxr[g] = *(const f32x4*)(gl +
                (size_t)((size_t)rg * 64 + g * 16 + sl * 4 + cb) * 256);

        for (int t = 0; t < T_; ++t) {
            f32x4 acc[4];
            #pragma unroll
            for (int g = 0; g < 4; ++g) acc[g] = gxr[g];
            if (t + 1 < T_) {
                #pragma unroll
                for (int g = 0; g < 4; ++g)
                    gxr[g] = *(const f32x4*)(gl +
                        (size_t)(((t + 1) * 8 + rg) * 64 + g * 16 + sl * 4 + cb) * 256);
            }

            #pragma unroll
            for (int kb = 0; kb < 8; ++kb) {
                frag a = *(const frag*)&h2[t & 1][lrow][kb * 32 + lhi * 8];
                #pragma unroll
                for (int g = 0; g < 4; ++g)
                    acc[g] = __builtin_amdgcn_mfma_f32_16x16x32_bf16(
                        a, br[kb & 3][g], acc[g], 0, 0, 0);
                // refill slot with phase +4 (lands during poll/epilogue window)
                const int tn = (kb < 4) ? t : t + 1;
                const int kn = (kb < 4) ? kb + 4 : kb - 4;
                if (tn < T_) {
                    #pragma unroll
                    for (int g = 0; g < 4; ++g)
                        br[kb & 3][g] = *(const frag*)(wl +
                            (size_t)((tn * 8 + kn) * 64 + g * 16 + sl * 4 + cb) * 512);
                }
            }

            // in-wave epilogue (no barrier, no reduce)
            float hv[4];
            unsigned short hb[4];
            #pragma unroll
            for (int rgi = 0; rgi < 4; ++rgi) {
                float i_ = __builtin_amdgcn_rcpf(1.f + __expf(-acc[0][rgi]));
                float f_ = __builtin_amdgcn_rcpf(1.f + __expf(-acc[1][rgi]));
                float o_ = __builtin_amdgcn_rcpf(1.f + __expf(-acc[2][rgi]));
                float gt = 1.f - 2.f * __builtin_amdgcn_rcpf(__expf(2.f * acc[3][rgi]) + 1.f);
                float c  = f_ * cst[rgi] + i_ * gt;
                cst[rgi] = c;
                float tc = 1.f - 2.f * __builtin_amdgcn_rcpf(__expf(2.f * c) + 1.f);
                hv[rgi] = o_ * tc;
                hb[rgi] = bf16u(hv[rgi]);
            }
            if (t + 1 < T_) {   // batched publishes first: one visibility latency
                #pragma unroll
                for (int rgi = 0; rgi < 4; ++rgi)
                    __hip_atomic_store(&pub[(size_t)(r0 + lhi * 4 + rgi) * H_ + colb],
                                       ((unsigned)(t + 1) << 16) | hb[rgi],
                                       __ATOMIC_RELAXED, __HIP_MEMORY_SCOPE_AGENT);
            }
            #pragma unroll
            for (int rgi = 0; rgi < 4; ++rgi) {
                const int row = lhi * 4 + rgi;
                out[(size_t)(t * B_ + r0 + row) * H_ + colb] = hv[rgi];
                h2[(t + 1) & 1][row][colb] = hb[rgi];
            }
            if (t == T_ - 1) {
                #pragma unroll
                for (int rgi = 0; rgi < 4; ++rgi) {
                    const int row = lhi * 4 + rgi;
                    out[(size_t)T_ * B_ * H_ + (size_t)(r0 + row) * H_ + colb] = hv[rgi];
                    out[(size_t)T_ * B_ * H_ + B_ * H_ + (size_t)(r0 + row) * H_ + colb] = cst[rgi];
                }
            }

            BARRIER_SEQ();   // single per-step barrier
        }
    } else {
        // ======================= poller role =======================
        const int ltid = tid - 256;   // 0..255
        int prow[12], pcol[12];
        #pragma unroll
        for (int k = 0; k < 12; ++k) {
            int w  = ltid + k * 256;      // 16 rows x 192 foreign cols
            int rr = w / 192;
            int fc = w - rr * 192;
            prow[k] = rr;
            pcol[k] = fc + (fc >= oc0 ? 64 : 0);
        }

        for (int t = 0; t < T_; ++t) {
            if (t + 1 < T_) {
                // round-12 proven batched poll: all 12 loads per round
                const unsigned want = (unsigned)(t + 1);
                while (true) {
                    unsigned vv[12];
                    #pragma unroll
                    for (int k = 0; k < 12; ++k)
                        vv[k] = __hip_atomic_load(
                            &pub[(size_t)(r0 + prow[k]) * H_ + pcol[k]],
                            __ATOMIC_RELAXED, __HIP_MEMORY_SCOPE_AGENT);
                    unsigned miss = 0;
                    #pragma unroll
                    for (int k = 0; k < 12; ++k) {
                        if ((vv[k] >> 16) == want)
                            h2[(t + 1) & 1][prow[k]][pcol[k]] =
                                (unsigned short)(vv[k] & 0xFFFFu);   // idempotent
                        else
                            miss = 1u;
                    }
                    if (!__any((int)miss)) break;
                }
            }

            BARRIER_SEQ();   // single per-step barrier
        }
    }
}

extern "C" void kernel_launch(void* const* d_in, const int* in_sizes, int n_in,
                              void* d_out, int out_size, void* d_ws, size_t ws_size,
                              hipStream_t stream) {
    const float* x  = (const float*)d_in[0];
    const float* h0 = (const float*)d_in[1];
    const float* c0 = (const float*)d_in[2];
    const float* Wi = (const float*)d_in[3];
    const float* bi = (const float*)d_in[4];
    const float* Wh = (const float*)d_in[5];
    const float* bh = (const float*)d_in[6];
    float* out = (float*)d_out;

    float*          Gxp = (float*)d_ws;                               // 64 MiB
    unsigned short* Whp = (unsigned short*)((char*)d_ws + 67108864);  // 64 MiB
    unsigned int*   pub = (unsigned int*)((char*)d_ws + 134217728);   // 128 KiB

    hipMemsetAsync(pub, 0, 131072, stream);
    lstm_pre<<<dim3(NP1 + NRP), dim3(512), 0, stream>>>(x, Wi, bi, bh, Wh, Gxp, Whp);
    lstm_rec<<<dim3(32), dim3(512), 0, stream>>>(h0, c0, Whp, Gxp, out, pub);
}

// Round 19
// 484.589 us; speedup vs baseline: 1.4588x; 1.4588x over previous
//
#include <hip/hip_runtime.h>
#include <hip/hip_bf16.h>
#include <cmath>

#define T_  128
#define B_  128
#define I_  256
#define H_  256
#define G4_ 1024

#define NP1 512    // phase1 blocks: (t, col-quarter)
#define NRP 8192   // repack blocks: 64 per t

using frag  = __attribute__((ext_vector_type(8))) short;   // 8 bf16 = 4 VGPR
using f32x4 = __attribute__((ext_vector_type(4))) float;
using u32x4 = __attribute__((ext_vector_type(4))) unsigned int;

__device__ __forceinline__ unsigned short bf16u(float f) {
    __hip_bfloat16 b = __float2bfloat16(f);
    return __builtin_bit_cast(unsigned short, b);
}

#define BARRIER_SEQ() do {                                   \
    __builtin_amdgcn_sched_barrier(0);                       \
    asm volatile("s_waitcnt lgkmcnt(0)" ::: "memory");       \
    __builtin_amdgcn_s_barrier();                            \
    __builtin_amdgcn_sched_barrier(0);                       \
} while (0)

// ================= Fused pre-pass (round-16 best) ==============================
// Blocks 0..511 : phase1-MFMA. Block (t = bid>>2, q = bid&3) computes
//   Gxp[t][:, cols q*256..+256] = bf16mfma(x[t], Wi[t]) + bi + bh, written
//   directly in MFMA C/D fragment layout (coalesced f32x4 stores). Wi staged
//   per-kb into LDS in B-fragment layout (double-buffered, ds_write_b128,
//   reused by all 8 row-waves — fixes round-13's uncoalesced B loads).
// Blocks 512+   : repack Wh fp32 -> bf16 B-fragments.
__global__ __launch_bounds__(512)
void lstm_pre(const float* __restrict__ x, const float* __restrict__ Wi,
              const float* __restrict__ bi, const float* __restrict__ bh,
              const float* __restrict__ Wh,
              float* __restrict__ Gxp, unsigned short* __restrict__ Whp)
{
    const int bid = blockIdx.x;
    const int tid = threadIdx.x;

    if (bid >= NP1) {
        // ---------------- repack role ----------------
        const int pbid = bid - NP1;
        const int tt   = pbid >> 6;
        const int j64  = pbid & 63;
        const int gid  = tt * 32768 + j64 * 512 + tid;
        const int lane = gid & 63;
        const int kb   = (gid >> 12) & 7;
        const int nb   = (gid >> 6) & 63;
        const int k0   = kb * 32 + (lane >> 4) * 8;
        const int col  = nb * 16 + (lane & 15);
        const float* src = Wh + (size_t)(tt * I_ + k0) * G4_ + col;
        unsigned short v[8];
        #pragma unroll
        for (int j = 0; j < 8; ++j) v[j] = bf16u(src[(size_t)j * G4_]);
        uint4 o;
        o.x = v[0] | ((unsigned)v[1] << 16);
        o.y = v[2] | ((unsigned)v[3] << 16);
        o.z = v[4] | ((unsigned)v[5] << 16);
        o.w = v[6] | ((unsigned)v[7] << 16);
        *(uint4*)(Whp + (size_t)gid * 8) = o;
        return;
    }

    // ---------------- phase1-MFMA role ----------------
    __shared__ unsigned short ws[2][16][64][8];   // 32KB

    const int t    = bid >> 2;
    const int q    = bid & 3;
    const int wv   = tid >> 6;
    const int lane = tid & 63;
    const int lrow = lane & 15;
    const int lhi  = lane >> 4;

    frag af[8];
    #pragma unroll
    for (int kb = 0; kb < 8; ++kb) {
        const float* ap = x + ((size_t)(t * B_ + wv * 16 + lrow) * I_ + kb * 32 + lhi * 8);
        float4 f0 = *(const float4*)ap;
        float4 f1 = *(const float4*)(ap + 4);
        u32x4 p;
        p.x = bf16u(f0.x) | ((unsigned)bf16u(f0.y) << 16);
        p.y = bf16u(f0.z) | ((unsigned)bf16u(f0.w) << 16);
        p.z = bf16u(f1.x) | ((unsigned)bf16u(f1.y) << 16);
        p.w = bf16u(f1.z) | ((unsigned)bf16u(f1.w) << 16);
        af[kb] = __builtin_bit_cast(frag, p);
    }

    f32x4 acc[16];
    #pragma unroll
    for (int n = 0; n < 16; ++n) {
        const int gc = (q * 16 + n) * 16 + lrow;
        const float b = bi[(size_t)t * G4_ + gc] + bh[(size_t)t * G4_ + gc];
        acc[n] = (f32x4){b, b, b, b};
    }

    auto stage = [&](int kb, int b) {
        #pragma unroll
        for (int p = 0; p < 2; ++p) {
            const int task = p * 512 + tid;
            const int colL = task & 255;
            const int khi  = task >> 8;
            const float* src = Wi + ((size_t)(t * I_ + kb * 32 + khi * 8) * G4_
                                     + q * 256 + colL);
            unsigned short v[8];
            #pragma unroll
            for (int j = 0; j < 8; ++j) v[j] = bf16u(src[(size_t)j * G4_]);
            uint4 o;
            o.x = v[0] | ((unsigned)v[1] << 16);
            o.y = v[2] | ((unsigned)v[3] << 16);
            o.z = v[4] | ((unsigned)v[5] << 16);
            o.w = v[6] | ((unsigned)v[7] << 16);
            const int nbh = colL >> 4;
            const int lw  = (colL & 15) | (khi << 4);
            *(uint4*)&ws[b][nbh][lw][0] = o;
        }
    };

    stage(0, 0);
    __syncthreads();
    for (int kb = 0; kb < 8; ++kb) {
        if (kb < 7) stage(kb + 1, (kb + 1) & 1);
        #pragma unroll
        for (int n = 0; n < 16; ++n) {
            frag bf = *(const frag*)&ws[kb & 1][n][lane][0];
            acc[n] = __builtin_amdgcn_mfma_f32_16x16x32_bf16(af[kb], bf, acc[n], 0, 0, 0);
        }
        __syncthreads();
    }

    #pragma unroll
    for (int n = 0; n < 16; ++n)
        *(f32x4*)&Gxp[(((size_t)t * 8 + wv) * 64 + q * 16 + n) * 256 + lane * 4] = acc[n];
}

// ================= Phase 2: column-split recurrence (round-16 best, verbatim) ==
// 32 blocks (rg=bid&7 row-group, sl=bid>>3 col-slice) x 512 threads.
// kh-split (K-halves across wave groups) is LOAD-BEARING: each wave covers its
// 4 kb per step, so ring refills issued at step t are consumed at t+1 — a full
// step of latency hiding (round-18's full-K variant shrank this to ~100cy and
// lost 55%). Exchange exclusively via __hip_atomic_load/store(RELAXED, AGENT)
// — the only proven-correct mechanism (rounds 8/9/11 deadlocked on sc-flag
// paths). Poll loads all 12 tagged words unconditionally per round (one LLC
// latency — round-12's fix of round-6's serialized polling). Epilogue computes
// all 4 h/c first, then fires the 4 publishes back-to-back.
__global__ __launch_bounds__(512, 1)
void lstm_rec(const float* __restrict__ h0, const float* __restrict__ c0in,
              const unsigned short* __restrict__ Whp,
              const float* __restrict__ Gxp, float* __restrict__ out,
              unsigned int* __restrict__ pub)
{
    __shared__ unsigned short h2[2][16][272];   // double-buffered bf16 h rows
    __shared__ float red[4][4][256];            // [cb][g][lane*4] K-hi partials

    const int tid  = threadIdx.x;
    const int wv   = tid >> 6;
    const int lane = tid & 63;
    const int rg   = blockIdx.x & 7;
    const int sl   = blockIdx.x >> 3;
    const int r0   = rg * 16;
    const int oc0  = sl * 64;
    const int lrow = lane & 15;
    const int lhi  = lane >> 4;

    const int kh = wv >> 2;          // K-half: 0 -> kb 0..3, 1 -> kb 4..7
    const int cb = wv & 3;           // 16-col fragment within own 64 cols

    {   // stage h0 -> h2[0] (full 256 cols)
        int row = tid >> 5;
        int cc  = (tid & 31) * 8;
        #pragma unroll
        for (int j = 0; j < 8; ++j)
            h2[0][row][cc + j] = bf16u(h0[(size_t)(r0 + row) * H_ + cc + j]);
    }

    float cst[4] = {0.f, 0.f, 0.f, 0.f};
    if (kh == 0) {
        #pragma unroll
        for (int rgi = 0; rgi < 4; ++rgi)
            cst[rgi] = c0in[(size_t)(r0 + lhi * 4 + rgi) * H_ + oc0 + cb * 16 + lrow];
    }

    // poll targets (K-hi threads): 12 foreign words each (16 rows x 192 cols)
    int prow[12], pcol[12];
    if (kh == 1) {
        const int ltid = tid - 256;
        #pragma unroll
        for (int k = 0; k < 12; ++k) {
            int w  = ltid + k * 256;
            int rr = w / 192;
            int fc = w - rr * 192;
            prow[k] = rr;
            pcol[k] = fc + (fc >= oc0 ? 64 : 0);
        }
    }

    const unsigned short* wl = Whp + (size_t)lane * 8;
    const float*          gl = Gxp + (size_t)lane * 4;

    // 4-deep weight fragment ring: br[kbl][g], kb = kh*4 + kbl
    frag br[4][4];
    #pragma unroll
    for (int kbl = 0; kbl < 4; ++kbl)
        #pragma unroll
        for (int g = 0; g < 4; ++g)
            br[kbl][g] = *(const frag*)(wl +
                (size_t)((kh * 4 + kbl) * 64 + g * 16 + sl * 4 + cb) * 512);

    f32x4 gxr[4];
    if (kh == 0) {
        #pragma unroll
        for (int g = 0; g < 4; ++g)
            gxr[g] = *(const f32x4*)(gl +
                (size_t)((size_t)rg * 64 + g * 16 + sl * 4 + cb) * 256);
    }

    __syncthreads();

    for (int t = 0; t < T_; ++t) {
        f32x4 acc[4];
        if (kh == 0) {
            #pragma unroll
            for (int g = 0; g < 4; ++g) acc[g] = gxr[g];
            if (t + 1 < T_) {
                #pragma unroll
                for (int g = 0; g < 4; ++g)
                    gxr[g] = *(const f32x4*)(gl +
                        (size_t)(((t + 1) * 8 + rg) * 64 + g * 16 + sl * 4 + cb) * 256);
            }
        } else {
            #pragma unroll
            for (int g = 0; g < 4; ++g) acc[g] = (f32x4){0.f, 0.f, 0.f, 0.f};
        }

        #pragma unroll
        for (int kbl = 0; kbl < 4; ++kbl) {
            const int kb = kh * 4 + kbl;
            frag a = *(const frag*)&h2[t & 1][lrow][kb * 32 + lhi * 8];
            #pragma unroll
            for (int g = 0; g < 4; ++g)
                acc[g] = __builtin_amdgcn_mfma_f32_16x16x32_bf16(
                    a, br[kbl][g], acc[g], 0, 0, 0);
            if (t + 1 < T_) {   // refill slot for next step (full-step lead time)
                #pragma unroll
                for (int g = 0; g < 4; ++g)
                    br[kbl][g] = *(const frag*)(wl +
                        (size_t)(((t + 1) * 8 + kb) * 64 + g * 16 + sl * 4 + cb) * 512);
            }
        }

        if (kh == 1) {   // stash K-hi partials
            #pragma unroll
            for (int g = 0; g < 4; ++g)
                *(f32x4*)&red[cb][g][lane * 4] = acc[g];
        }

        BARRIER_SEQ();   // barrier A

        if (kh == 0) {
            // reduce + epilogue; publishes batched FIRST, then local stores
            #pragma unroll
            for (int g = 0; g < 4; ++g)
                acc[g] += *(const f32x4*)&red[cb][g][lane * 4];
            const int colb = oc0 + cb * 16 + lrow;
            float hv[4];
            unsigned short hb[4];
            #pragma unroll
            for (int rgi = 0; rgi < 4; ++rgi) {
                float gi = acc[0][rgi], gf = acc[1][rgi];
                float go = acc[2][rgi], gg = acc[3][rgi];
                float i_ = __builtin_amdgcn_rcpf(1.f + __expf(-gi));
                float f_ = __builtin_amdgcn_rcpf(1.f + __expf(-gf));
                float o_ = __builtin_amdgcn_rcpf(1.f + __expf(-go));
                float gt = 1.f - 2.f * __builtin_amdgcn_rcpf(__expf(2.f * gg) + 1.f);
                float c  = f_ * cst[rgi] + i_ * gt;
                cst[rgi] = c;
                float tc = 1.f - 2.f * __builtin_amdgcn_rcpf(__expf(2.f * c) + 1.f);
                float h  = o_ * tc;
                hv[rgi] = h;
                hb[rgi] = bf16u(h);
            }
            if (t + 1 < T_) {   // 4 publishes back-to-back: one visibility latency
                #pragma unroll
                for (int rgi = 0; rgi < 4; ++rgi)
                    __hip_atomic_store(&pub[(size_t)(r0 + lhi * 4 + rgi) * H_ + colb],
                                       ((unsigned)(t + 1) << 16) | hb[rgi],
                                       __ATOMIC_RELAXED, __HIP_MEMORY_SCOPE_AGENT);
            }
            #pragma unroll
            for (int rgi = 0; rgi < 4; ++rgi) {
                const int row = lhi * 4 + rgi;
                out[(size_t)(t * B_ + r0 + row) * H_ + colb] = hv[rgi];
                h2[(t + 1) & 1][row][colb] = hb[rgi];
            }
            if (t == T_ - 1) {
                #pragma unroll
                for (int rgi = 0; rgi < 4; ++rgi) {
                    const int row = lhi * 4 + rgi;
                    out[(size_t)T_ * B_ * H_ + (size_t)(r0 + row) * H_ + colb] = hv[rgi];
                    out[(size_t)T_ * B_ * H_ + B_ * H_ + (size_t)(r0 + row) * H_ + colb] = cst[rgi];
                }
            }
        } else if (t + 1 < T_) {
            // poll foreign slices of h_{t+1}: BATCHED — all 12 loads per round
            const unsigned want = (unsigned)(t + 1);
            while (true) {
                unsigned vv[12];
                #pragma unroll
                for (int k = 0; k < 12; ++k)
                    vv[k] = __hip_atomic_load(
                        &pub[(size_t)(r0 + prow[k]) * H_ + pcol[k]],
                        __ATOMIC_RELAXED, __HIP_MEMORY_SCOPE_AGENT);
                unsigned miss = 0;
                #pragma unroll
                for (int k = 0; k < 12; ++k) {
                    if ((vv[k] >> 16) == want)
                        h2[(t + 1) & 1][prow[k]][pcol[k]] =
                            (unsigned short)(vv[k] & 0xFFFFu);
                    else
                        miss = 1u;
                }
                if (!__any((int)miss)) break;
            }
        }

        BARRIER_SEQ();   // barrier B
    }
}

extern "C" void kernel_launch(void* const* d_in, const int* in_sizes, int n_in,
                              void* d_out, int out_size, void* d_ws, size_t ws_size,
                              hipStream_t stream) {
    const float* x  = (const float*)d_in[0];
    const float* h0 = (const float*)d_in[1];
    const float* c0 = (const float*)d_in[2];
    const float* Wi = (const float*)d_in[3];
    const float* bi = (const float*)d_in[4];
    const float* Wh = (const float*)d_in[5];
    const float* bh = (const float*)d_in[6];
    float* out = (float*)d_out;

    float*          Gxp = (float*)d_ws;                               // 64 MiB
    unsigned short* Whp = (unsigned short*)((char*)d_ws + 67108864);  // 64 MiB
    unsigned int*   pub = (unsigned int*)((char*)d_ws + 134217728);   // 128 KiB

    hipMemsetAsync(pub, 0, 131072, stream);
    lstm_pre<<<dim3(NP1 + NRP), dim3(512), 0, stream>>>(x, Wi, bi, bh, Wh, Gxp, Whp);
    lstm_rec<<<dim3(32), dim3(512), 0, stream>>>(h0, c0, Whp, Gxp, out, pub);
}